// Round 1
// baseline (199.379 us; speedup 1.0000x reference)
//
#include <hip/hip_runtime.h>
#include <math.h>

#define B_  2
#define S_  2048
#define D_  1024
#define H_  16
#define DH_ 64

typedef unsigned short u16;
typedef unsigned int   u32;
typedef _Float16       f16;
typedef _Float16 half8  __attribute__((ext_vector_type(8)));
typedef _Float16 half4  __attribute__((ext_vector_type(4)));
typedef float    f32x4  __attribute__((ext_vector_type(4)));

#if __has_builtin(__builtin_amdgcn_exp2f)
#define EXP2(x) __builtin_amdgcn_exp2f(x)
#else
#define EXP2(x) exp2f(x)
#endif

__device__ __forceinline__ u16 h_bits(f16 h){ return __builtin_bit_cast(u16, h); }

// ---------------------------------------------------------------------------
// Kernel 1: prep = split_x + convert_w fused (UNCHANGED from previous round).
// ---------------------------------------------------------------------------
__global__ __launch_bounds__(256) void prep_kernel(
    const float* __restrict__ X,
    const float* __restrict__ Wq, const float* __restrict__ Wk,
    const float* __restrict__ Wv,
    u16* __restrict__ Xhi, u16* __restrict__ Xlo, u16* __restrict__ Wt)
{
    __shared__ float Wf[64][65];
    const int bid = blockIdx.x;
    const int c   = threadIdx.x;

    if (bid < 4096){
        const int idx = bid * 256 + c;
        float4 v = ((const float4*)X)[idx];
        float fv[4] = {v.x, v.y, v.z, v.w};
        u16 hh[4], ll[4];
        #pragma unroll
        for (int j = 0; j < 4; ++j){
            f16 hi = (f16)fv[j];
            hh[j] = h_bits(hi);
            ll[j] = h_bits((f16)(fv[j] - (float)hi));
        }
        uint2 ph, pl;
        ph.x = hh[0] | ((u32)hh[1] << 16);
        ph.y = hh[2] | ((u32)hh[3] << 16);
        pl.x = ll[0] | ((u32)ll[1] << 16);
        pl.y = ll[2] | ((u32)ll[3] << 16);
        ((uint2*)Xhi)[idx] = ph;
        ((uint2*)Xlo)[idx] = pl;
        return;
    }

    const int wb = bid - 4096;          // 0..767
    const int d0 = (wb & 15) * 64;
    const int h  = (wb >> 4) & 15;
    const int which = wb >> 8;
    const float* src = (which == 0) ? Wq : (which == 1) ? Wk : Wv;
    src += (size_t)h * D_ * DH_;

    #pragma unroll
    for (int it = 0; it < 4; ++it){
        int d  = (c >> 4) + 16 * it;
        int e4 = (c & 15) * 4;
        float4 v = *(const float4*)(src + (size_t)(d0 + d) * DH_ + e4);
        Wf[d][e4+0] = v.x; Wf[d][e4+1] = v.y; Wf[d][e4+2] = v.z; Wf[d][e4+3] = v.w;
    }
    __syncthreads();
    u16* dst = Wt + (size_t)(which * H_ + h) * DH_ * D_;
    #pragma unroll
    for (int it = 0; it < 4; ++it){
        int e  = (c >> 4) + 16 * it;
        int d4 = (c & 15) * 4;
        u16 q[4];
        #pragma unroll
        for (int j = 0; j < 4; ++j)
            q[j] = h_bits((f16)(Wf[d4 + j][e] * 64.0f));
        u32* p = (u32*)(dst + (size_t)e * D_ + d0 + d4);
        p[0] = q[0] | ((u32)q[1] << 16);
        p[1] = q[2] | ((u32)q[3] << 16);
    }
}

// ---------------------------------------------------------------------------
// Kernel 2 (REWRITTEN): QKV projection as one flat GEMM, 256x256 8-phase
// schedule (T2+T3+T4+T5).  hi/lo 2-term split flattened into K=2048:
//   k-tiles 0..15 stage from Xhi, 16..31 from Xlo; B re-reads Wt (k&1023).
// 512 threads = 8 waves (2M x 4N); per-wave output 128x64 (acc[8][4]).
// BK=64 stored as two 32-k halves of 16 KiB each; LDS = 128 KiB dbuf.
// T2 swizzle (involution byte ^= ((byte>>7)&3)<<4 within each 16 KiB half)
// applied to the per-lane GLOBAL source of global_load_lds (linear LDS dest)
// and identically on the ds_read address -> max 2-way bank conflict.
// Ring: during tile t phases p0..p3 stage (t+1).A.k1, (t+1).B.k1,
// (t+2).A.k0, (t+2).B.k0; boundary wait = vmcnt(4) (tile t+1 fully landed,
// tile t+2's k0 halves stay in flight).  vmcnt never drained to 0 until the
// t=30 epilogue.  Each staged half-region's last reader finished at the
// previous closing barrier -> no write-after-read race.
// ---------------------------------------------------------------------------
__device__ __forceinline__ void gload16(const void* g, void* l){
    __builtin_amdgcn_global_load_lds(
        (const __attribute__((address_space(1))) void*)g,
        (__attribute__((address_space(3))) void*)l, 16, 0, 0);
}

__device__ __forceinline__ half8 frag16(const char* hb, int row, int quad){
    // swizzled read: logical byte = row*64 + quad*16, phys = swz(logical)
    int off = row * 64 + ((quad * 16) ^ ((row & 6) << 3));
    return __builtin_bit_cast(half8, *(const uint4*)(hb + off));
}

#define FENCE() asm volatile("" ::: "memory")
#define BARX()  do{ FENCE(); __builtin_amdgcn_s_barrier(); FENCE(); }while(0)
#define WAIT_VM4() asm volatile("s_waitcnt vmcnt(4)" ::: "memory")
#define WAIT_VM0() asm volatile("s_waitcnt vmcnt(0)" ::: "memory")

#define STAGE_A(t_, kh_) do{ \
    const int _t = (t_); \
    const int _gk = ((_t & 15) << 6) + ((kh_) << 5); \
    const u16* _g0 = ((_t < 16) ? xa0h : xa0l) + _gk; \
    const u16* _g1 = ((_t < 16) ? xa1h : xa1l) + _gk; \
    char* _l = AsB + ((_t & 1) << 15) + ((kh_) << 14); \
    gload16(_g0, _l + ldw0); \
    gload16(_g1, _l + ldw1); \
}while(0)

#define STAGE_B(t_, kh_) do{ \
    const int _t = (t_); \
    const int _gk = ((_t & 15) << 6) + ((kh_) << 5); \
    char* _l = BsB + ((_t & 1) << 15) + ((kh_) << 14); \
    gload16(wb0 + _gk, _l + ldw0); \
    gload16(wb1 + _gk, _l + ldw1); \
}while(0)

#define READ_B(bh_) do{ \
    _Pragma("unroll") \
    for (int nf_ = 0; nf_ < 4; ++nf_) \
        bfr[nf_] = frag16((bh_), wn * 64 + nf_ * 16 + ln, quad); \
}while(0)

#define READ_A(ah_, mbase_) do{ \
    _Pragma("unroll") \
    for (int mi_ = 0; mi_ < 4; ++mi_) \
        af[mi_] = frag16((ah_), wm * 128 + ((mbase_) + mi_) * 16 + ln, quad); \
}while(0)

#define MFMA_BLOCK(mbase_) do{ \
    BARX(); \
    asm volatile("s_waitcnt lgkmcnt(0)" ::: "memory"); \
    __builtin_amdgcn_sched_barrier(0); \
    __builtin_amdgcn_s_setprio(1); \
    _Pragma("unroll") \
    for (int mi_ = 0; mi_ < 4; ++mi_){ \
        _Pragma("unroll") \
        for (int nf_ = 0; nf_ < 4; ++nf_) \
            acc[(mbase_) + mi_][nf_] = __builtin_amdgcn_mfma_f32_16x16x32_f16( \
                af[mi_], bfr[nf_], acc[(mbase_) + mi_][nf_], 0, 0, 0); \
    } \
    __builtin_amdgcn_s_setprio(0); \
}while(0)

__global__ __launch_bounds__(512, 2) void proj_kernel(
    const u16* __restrict__ Xhi, const u16* __restrict__ Xlo,
    const u16* __restrict__ Wt,
    const float* __restrict__ bq, const float* __restrict__ bk,
    const float* __restrict__ bv,
    f16* __restrict__ Qh, f16* __restrict__ Kh, f16* __restrict__ Vt)
{
    __shared__ __align__(16) char AsB[65536];   // [2 dbuf][2 khalf][256][32] f16
    __shared__ __align__(16) char BsB[65536];

    const int tid  = threadIdx.x;
    const int lane = tid & 63;
    const int w    = tid >> 6;          // 0..7
    const int wm   = w >> 2;            // 0..1 (M half)
    const int wn   = w & 3;             // 0..3 (N quarter)
    const int quad = lane >> 4;
    const int ln   = lane & 15;

    // XCD swizzle: 192 blocks -> 8 XCDs x 24 contiguous tiles
    const int bid = blockIdx.x;
    const int swz = (bid & 7) * 24 + (bid >> 3);
    const int m0  = (swz / 12) * 256;
    const int c0  = (swz % 12) * 256;

    // staging source precompute: lane's dest granule L (linear) holds the
    // element at logical position P = swz(L); two loads j=0,1 per half.
    const int Lr0 = w * 1024 + lane * 16;
    const int Lr1 = (8 + w) * 1024 + lane * 16;
    const int P0  = Lr0 ^ (((Lr0 >> 7) & 3) << 4);
    const int P1  = Lr1 ^ (((Lr1 >> 7) & 3) << 4);
    const int row0 = P0 >> 6,        row1 = P1 >> 6;
    const int ko0  = (P0 & 63) >> 1, ko1  = (P1 & 63) >> 1;

    const u16* xa0h = Xhi + (size_t)(m0 + row0) * D_ + ko0;
    const u16* xa1h = Xhi + (size_t)(m0 + row1) * D_ + ko1;
    const u16* xa0l = Xlo + (size_t)(m0 + row0) * D_ + ko0;
    const u16* xa1l = Xlo + (size_t)(m0 + row1) * D_ + ko1;
    const u16* wb0  = Wt  + (size_t)(c0 + row0) * D_ + ko0;
    const u16* wb1  = Wt  + (size_t)(c0 + row1) * D_ + ko1;

    const int ldw0 = w * 1024;          // wave-uniform LDS sub-bases
    const int ldw1 = (8 + w) * 1024;

    f32x4 acc[8][4];
    #pragma unroll
    for (int i = 0; i < 8; ++i)
        #pragma unroll
        for (int j = 0; j < 4; ++j)
            acc[i][j] = (f32x4){0.f, 0.f, 0.f, 0.f};

    // prologue: tile0 complete (8 loads) + tile1 k0 halves (4 loads)
    STAGE_A(0, 0); STAGE_B(0, 0); STAGE_A(0, 1); STAGE_B(0, 1);
    STAGE_A(1, 0); STAGE_B(1, 0);
    WAIT_VM4();                          // tile0 landed; tile1.k0 in flight
    BARX();

    half8 bfr[4], af[4];

    #pragma unroll 2
    for (int t = 0; t < 32; ++t){
        const char* Ah = AsB + ((t & 1) << 15);
        const char* Bh = BsB + ((t & 1) << 15);

        // phase 0: ks=0, m-frags 0..3
        READ_B(Bh); READ_A(Ah, 0);
        if (t < 31) STAGE_A(t + 1, 1);
        MFMA_BLOCK(0);
        BARX();

        // phase 1: ks=0, m-frags 4..7 (reuse bfr)
        READ_A(Ah, 4);
        if (t < 31) STAGE_B(t + 1, 1);
        MFMA_BLOCK(4);
        BARX();

        // phase 2: ks=1, m-frags 0..3
        READ_B(Bh + 16384); READ_A(Ah + 16384, 0);
        if (t < 30) STAGE_A(t + 2, 0);
        MFMA_BLOCK(0);
        BARX();

        // phase 3: ks=1, m-frags 4..7; boundary vmcnt before closing barrier
        READ_A(Ah + 16384, 4);
        if (t < 30) STAGE_B(t + 2, 0);
        MFMA_BLOCK(4);
        if (t < 30) { WAIT_VM4(); } else { WAIT_VM0(); }
        BARX();
    }

    // epilogue (same math as previous round; 8 m-frags x 4 n-frags)
    const float QSCALE = 0.125f * 1.44269504088896340736f;
    const float INV64  = 0.015625f;
    #pragma unroll
    for (int nf = 0; nf < 4; ++nf){
        int colg  = c0 + wn * 64 + nf * 16 + ln;
        int which = colg >> 10;          // uniform within the 16-col group
        int h     = (colg >> 6) & 15;
        int e     = colg & 63;
        const float* bp = (which == 0) ? bq : (which == 1) ? bk : bv;
        float bias = bp[h * DH_ + e];
        if (which < 2){
            f16* op = (which == 0) ? Qh : Kh;
            float scale = (which == 0) ? QSCALE : 1.0f;
            #pragma unroll
            for (int mf = 0; mf < 8; ++mf)
                #pragma unroll
                for (int r = 0; r < 4; ++r){
                    int sg = m0 + wm * 128 + mf * 16 + 4 * quad + r;
                    int b  = sg >> 11;
                    int s  = sg & (S_ - 1);
                    float val = (acc[mf][nf][r] * INV64 + bias) * scale;
                    op[((size_t)(b * H_ + h) * S_ + s) * DH_ + e] = (f16)val;
                }
        } else {
            // V: write transposed Vt[bh][e][t]; 4 consecutive s -> 8B store
            #pragma unroll
            for (int mf = 0; mf < 8; ++mf){
                int sg0 = m0 + wm * 128 + mf * 16 + 4 * quad;
                int b   = sg0 >> 11;
                int s0  = sg0 & (S_ - 1);
                u16 p[4];
                #pragma unroll
                for (int r = 0; r < 4; ++r)
                    p[r] = h_bits((f16)(acc[mf][nf][r] * INV64 + bias));
                uint2 pk;
                pk.x = p[0] | ((u32)p[1] << 16);
                pk.y = p[2] | ((u32)p[3] << 16);
                *(uint2*)((u16*)Vt + ((size_t)((b * H_ + h) * DH_ + e)) * S_ + s0) = pk;
            }
        }
    }
}

// ---------------------------------------------------------------------------
// Kernel 3: attention (UNCHANGED from previous round).
// ---------------------------------------------------------------------------
#define AKS 72

__global__ __launch_bounds__(256, 4) void attn_kernel(
    const f16* __restrict__ Qh, const f16* __restrict__ Kh,
    const f16* __restrict__ Vt, float* __restrict__ Out)
{
    __shared__ u16 Ks[64 * AKS];   // K tile [t][e]
    __shared__ u16 Vs[64 * AKS];   // V tile [e][t]

    const int tid  = threadIdx.x;
    const int lane = tid & 63;
    const int w    = tid >> 6;
    const int quad = lane >> 4;
    const int ln   = lane & 15;
    const int hb   = blockIdx.x;            // b*H + h  (XCD = hb % 8)
    const int i    = blockIdx.y;            // pair index
    const int h    = hb & 15;
    const int b    = hb >> 4;
    const int bh   = hb;
    const int sub  = w & 1;
    const int qbase = (w >> 1) ? (S_ - 32 * (i + 1) + 16 * sub)
                               : (32 * i + 16 * sub);
    const int vmax  = S_ - 32 * i - 1;      // highest t any wave's PV needs

    const u16* Qg = (const u16*)Qh + (size_t)bh * S_ * DH_;
    const u16* Kg = (const u16*)Kh + (size_t)bh * S_ * DH_;
    const u16* Vg = (const u16*)Vt + (size_t)bh * DH_ * S_;

    // Q fragments straight from global (B-operand: n=q=ln, k=d=32ks+8quad+j)
    half8 qf[2];
    #pragma unroll
    for (int ks = 0; ks < 2; ++ks)
        qf[ks] = __builtin_bit_cast(half8,
            *(const uint4*)(Qg + (size_t)(qbase + ln) * DH_ + 32 * ks + 8 * quad));

    // staging coords: thread covers K rows kr,kr+32 / V rows (e) kr,kr+32
    const int kr = tid >> 3;
    const int kc = (tid & 7) * 8;

    // prefetch tile 0 into registers
    uint4 kA = *(const uint4*)(Kg + (size_t)kr * DH_ + kc);
    uint4 kB = *(const uint4*)(Kg + (size_t)(kr + 32) * DH_ + kc);
    uint4 vA = *(const uint4*)(Vg + (size_t)kr * S_ + kc);
    uint4 vB = *(const uint4*)(Vg + (size_t)(kr + 32) * S_ + kc);

    float l_r = 0.f;
    f32x4 o_acc[4];
    #pragma unroll
    for (int nt = 0; nt < 4; ++nt) o_acc[nt] = (f32x4){0.f, 0.f, 0.f, 0.f};

    const int qrow   = qbase + ln;     // this lane's q (n-dim)
    const int pv_lim = qbase + 15;     // wave-uniform PV bound

    for (int t0 = 0; t0 < S_; t0 += 64){
        __syncthreads();               // all waves done reading prev tile
        *(uint4*)&Ks[kr * AKS + kc]        = kA;
        *(uint4*)&Ks[(kr + 32) * AKS + kc] = kB;
        if (t0 <= vmax){
            *(uint4*)&Vs[kr * AKS + kc]        = vA;
            *(uint4*)&Vs[(kr + 32) * AKS + kc] = vB;
        }
        // prefetch tile t0+64 (hidden behind this tile's compute)
        const int tn = t0 + 64;
        if (tn < S_){
            kA = *(const uint4*)(Kg + (size_t)(tn + kr) * DH_ + kc);
            kB = *(const uint4*)(Kg + (size_t)(tn + kr + 32) * DH_ + kc);
            if (tn <= vmax){
                vA = *(const uint4*)(Vg + (size_t)kr * S_ + tn + kc);
                vB = *(const uint4*)(Vg + (size_t)(kr + 32) * S_ + tn + kc);
            }
        }
        __syncthreads();               // LDS tile ready

        // S^T tile: A = K frags (m=t), B = Q frags (n=q), K=32 over d
        f32x4 sc[4];
        #pragma unroll
        for (int mt = 0; mt < 4; ++mt) sc[mt] = (f32x4){0.f, 0.f, 0.f, 0.f};
        #pragma unroll
        for (int ks = 0; ks < 2; ++ks)
            #pragma unroll
            for (int mt = 0; mt < 4; ++mt){
                half8 kf = __builtin_bit_cast(half8,
                    *(const uint4*)&Ks[(16 * mt + ln) * AKS + 32 * ks + 8 * quad]);
                sc[mt] = __builtin_amdgcn_mfma_f32_16x16x32_f16(kf, qf[ks], sc[mt], 0, 0, 0);
            }

        // p = exp2(s); denominator = plain running row-sum over ALL t
        #pragma unroll
        for (int mt = 0; mt < 4; ++mt)
            #pragma unroll
            for (int r = 0; r < 4; ++r)
                sc[mt][r] = EXP2(sc[mt][r]);
        float s = ((sc[0][0] + sc[0][1] + sc[0][2] + sc[0][3]) +
                   (sc[1][0] + sc[1][1] + sc[1][2] + sc[1][3])) +
                  ((sc[2][0] + sc[2][1] + sc[2][2] + sc[2][3]) +
                   (sc[3][0] + sc[3][1] + sc[3][2] + sc[3][3]));
        s += __shfl_xor(s, 16);
        s += __shfl_xor(s, 32);
        l_r += s;

        // PV per 16-t subtile; only the subtile starting AT qbase is partial
        #pragma unroll
        for (int mt = 0; mt < 4; ++mt){
            const int ts = t0 + 16 * mt;
            if (ts <= pv_lim){         // wave-uniform
                half4 pf;
                if (ts == qbase){      // wave-uniform: the one partial subtile
                    int tb = ts + 4 * quad;
                    #pragma unroll
                    for (int r = 0; r < 4; ++r)
                        pf[r] = (tb + r > qrow) ? (f16)0.f : (f16)sc[mt][r];
                } else {               // fully below diagonal: plain convert
                    #pragma unroll
                    for (int r = 0; r < 4; ++r)
                        pf[r] = (f16)sc[mt][r];
                }
                #pragma unroll
                for (int nt = 0; nt < 4; ++nt){
                    half4 vf = __builtin_bit_cast(half4,
                        *(const uint2*)&Vs[(16 * nt + ln) * AKS + 16 * mt + 4 * quad]);
                    o_acc[nt] = __builtin_amdgcn_mfma_f32_16x16x16f16(pf, vf, o_acc[nt], 0, 0, 0);
                }
            }
        }
    }

    // epilogue: o rows at q = qbase+4quad+r; l lives at lane ln=row
    #pragma unroll
    for (int r = 0; r < 4; ++r){
        float lv  = __shfl(l_r, (lane & 48) | (4 * quad + r));
        float inv = 1.0f / lv;
        int sg = qbase + 4 * quad + r;
        float* op = Out + ((size_t)b * S_ + sg) * D_ + h * DH_;
        #pragma unroll
        for (int nt = 0; nt < 4; ++nt)
            op[16 * nt + ln] = o_acc[nt][r] * inv;
    }
}

// ---------------------------------------------------------------------------
extern "C" void kernel_launch(void* const* d_in, const int* in_sizes, int n_in,
                              void* d_out, int out_size, void* d_ws, size_t ws_size,
                              hipStream_t stream)
{
    const float* X  = (const float*)d_in[0];
    const float* Wq = (const float*)d_in[1];
    const float* bq = (const float*)d_in[2];
    const float* Wk = (const float*)d_in[3];
    const float* bk = (const float*)d_in[4];
    const float* Wv = (const float*)d_in[5];
    const float* bv = (const float*)d_in[6];
    float* out = (float*)d_out;

    // workspace (46 MiB): Wt | Qh | Kh | Vt | Xhi | Xlo  (unchanged layout)
    u16* Wt  = (u16*)d_ws;                    // 3,145,728 u16
    f16* Qh  = (f16*)(Wt + 3145728);
    f16* Kh  = Qh + 4194304;
    f16* Vt  = Kh + 4194304;
    u16* Xhi = (u16*)(Vt + 4194304);
    u16* Xlo = Xhi + 4194304;

    prep_kernel<<<dim3(4096 + 768), 256, 0, stream>>>(X, Wq, Wk, Wv, Xhi, Xlo, Wt);
    proj_kernel<<<dim3(192), dim3(512), 0, stream>>>(Xhi, Xlo, Wt, bq, bk, bv, Qh, Kh, Vt);
    attn_kernel<<<dim3(32, 32), 256, 0, stream>>>(Qh, Kh, Vt, out);
}

// Round 2
// 194.124 us; speedup vs baseline: 1.0271x; 1.0271x over previous
//
#include <hip/hip_runtime.h>
#include <math.h>

#define B_  2
#define S_  2048
#define D_  1024
#define H_  16
#define DH_ 64

typedef unsigned short u16;
typedef unsigned int   u32;
typedef _Float16       f16;
typedef _Float16 half8  __attribute__((ext_vector_type(8)));
typedef _Float16 half4  __attribute__((ext_vector_type(4)));
typedef float    f32x4  __attribute__((ext_vector_type(4)));

#if __has_builtin(__builtin_amdgcn_exp2f)
#define EXP2(x) __builtin_amdgcn_exp2f(x)
#else
#define EXP2(x) exp2f(x)
#endif

__device__ __forceinline__ u16 h_bits(f16 h){ return __builtin_bit_cast(u16, h); }

// ---------------------------------------------------------------------------
// Kernel 1: prep = split_x + convert_w fused (UNCHANGED).
// ---------------------------------------------------------------------------
__global__ __launch_bounds__(256) void prep_kernel(
    const float* __restrict__ X,
    const float* __restrict__ Wq, const float* __restrict__ Wk,
    const float* __restrict__ Wv,
    u16* __restrict__ Xhi, u16* __restrict__ Xlo, u16* __restrict__ Wt)
{
    __shared__ float Wf[64][65];
    const int bid = blockIdx.x;
    const int c   = threadIdx.x;

    if (bid < 4096){
        const int idx = bid * 256 + c;
        float4 v = ((const float4*)X)[idx];
        float fv[4] = {v.x, v.y, v.z, v.w};
        u16 hh[4], ll[4];
        #pragma unroll
        for (int j = 0; j < 4; ++j){
            f16 hi = (f16)fv[j];
            hh[j] = h_bits(hi);
            ll[j] = h_bits((f16)(fv[j] - (float)hi));
        }
        uint2 ph, pl;
        ph.x = hh[0] | ((u32)hh[1] << 16);
        ph.y = hh[2] | ((u32)hh[3] << 16);
        pl.x = ll[0] | ((u32)ll[1] << 16);
        pl.y = ll[2] | ((u32)ll[3] << 16);
        ((uint2*)Xhi)[idx] = ph;
        ((uint2*)Xlo)[idx] = pl;
        return;
    }

    const int wb = bid - 4096;          // 0..767
    const int d0 = (wb & 15) * 64;
    const int h  = (wb >> 4) & 15;
    const int which = wb >> 8;
    const float* src = (which == 0) ? Wq : (which == 1) ? Wk : Wv;
    src += (size_t)h * D_ * DH_;

    #pragma unroll
    for (int it = 0; it < 4; ++it){
        int d  = (c >> 4) + 16 * it;
        int e4 = (c & 15) * 4;
        float4 v = *(const float4*)(src + (size_t)(d0 + d) * DH_ + e4);
        Wf[d][e4+0] = v.x; Wf[d][e4+1] = v.y; Wf[d][e4+2] = v.z; Wf[d][e4+3] = v.w;
    }
    __syncthreads();
    u16* dst = Wt + (size_t)(which * H_ + h) * DH_ * D_;
    #pragma unroll
    for (int it = 0; it < 4; ++it){
        int e  = (c >> 4) + 16 * it;
        int d4 = (c & 15) * 4;
        u16 q[4];
        #pragma unroll
        for (int j = 0; j < 4; ++j)
            q[j] = h_bits((f16)(Wf[d4 + j][e] * 64.0f));
        u32* p = (u32*)(dst + (size_t)e * D_ + d0 + d4);
        p[0] = q[0] | ((u32)q[1] << 16);
        p[1] = q[2] | ((u32)q[3] << 16);
    }
}

// ---------------------------------------------------------------------------
// Kernel 2 (R2): flat GEMM M=4096 N=3072 K=2048 (hi/lo folded into K).
// Tile 256x192 -> grid 16x16 = 256 blocks = exactly 1/CU (R1's 192-block
// grid idled 25% of CUs).  8 waves (2M x 4N), per-wave 128x96, acc[8][3].
// 4 phases per K-tile (BK=64 as two 32-k halves), 12 MFMA each.
// KEY CHANGE vs R1: no asm memory fences on the per-phase barriers, no asm
// lgkmcnt, no sched_barrier.  Every phase's fragments are ds_read INSIDE the
// previous phase's MFMA window (explicit register pipeline) so the LDS and
// MFMA pipes overlap instead of alternating (R1's fences serialized them ->
// MfmaUtil 27%).  Only the tile-boundary vmcnt keeps a "memory" clobber: it
// orders next-tile ds_reads after global_load_lds landing (+barrier).
// Ring: tile t stages (t+1).k1 at P0/P1 and (t+2).k0 at P2/P3; boundary
// vmcnt(3) leaves only (t+2).k0 in flight (FIFO => all of t+1 landed).
// WAR audit: each staged region's last reader retires >=1 closing barrier
// before the writer issues (per-region check in session notes).
// T2 swizzle unchanged (R1 measured 0 bank conflicts): involution
// byte ^= ((byte>>7)&3)<<4, applied to the per-lane GLOBAL source (LDS dest
// linear, rule #21) and identically on the ds_read address.
// ---------------------------------------------------------------------------
__device__ __forceinline__ void gload16(const void* g, void* l){
    __builtin_amdgcn_global_load_lds(
        (const __attribute__((address_space(1))) void*)g,
        (__attribute__((address_space(3))) void*)l, 16, 0, 0);
}

__device__ __forceinline__ half8 frag16(const char* hb, int row, int quad){
    // swizzled read: logical byte = row*64 + quad*16, phys = swz(logical)
    int off = row * 64 + ((quad * 16) ^ ((row & 6) << 3));
    return __builtin_bit_cast(half8, *(const uint4*)(hb + off));
}

#define BAR() __builtin_amdgcn_s_barrier()

#define STAGE_A(t_, kh_) do{ \
    const int _t = (t_); \
    const int _gk = ((_t & 15) << 6) + ((kh_) << 5); \
    const u16* _g0 = ((_t < 16) ? xa0h : xa0l) + _gk; \
    const u16* _g1 = ((_t < 16) ? xa1h : xa1l) + _gk; \
    char* _l = AsB + ((_t & 1) ? 32768 : 0) + ((kh_) << 14); \
    gload16(_g0, _l + ldw0); \
    gload16(_g1, _l + ldw1); \
}while(0)

#define STAGE_B(t_, kh_) do{ \
    const int _gk = (((t_) & 15) << 6) + ((kh_) << 5); \
    char* _l = BsB + (((t_) & 1) ? 24576 : 0) + ((kh_) ? 12288 : 0); \
    gload16(wb0 + _gk, _l + ldw0); \
    if (w < 4) gload16(wb1 + _gk, _l + ldw1); \
}while(0)

#define RD_B(dst_, base_) do{ \
    _Pragma("unroll") \
    for (int nf_ = 0; nf_ < 3; ++nf_) \
        dst_[nf_] = frag16((base_), wn * 48 + nf_ * 16 + ln, quad); \
}while(0)

#define RD_A(dst_, base_, mo_) do{ \
    _Pragma("unroll") \
    for (int mi_ = 0; mi_ < 4; ++mi_) \
        dst_[mi_] = frag16((base_), wm * 128 + (mo_) + mi_ * 16 + ln, quad); \
}while(0)

#define MFMA12(a_, b_, mb_) do{ \
    _Pragma("unroll") \
    for (int mi_ = 0; mi_ < 4; ++mi_) \
        _Pragma("unroll") \
        for (int nf_ = 0; nf_ < 3; ++nf_) \
            acc[(mb_) + mi_][nf_] = __builtin_amdgcn_mfma_f32_16x16x32_f16( \
                a_[mi_], b_[nf_], acc[(mb_) + mi_][nf_], 0, 0, 0); \
}while(0)

__global__ __launch_bounds__(512, 2) void proj_kernel(
    const u16* __restrict__ Xhi, const u16* __restrict__ Xlo,
    const u16* __restrict__ Wt,
    const float* __restrict__ bq, const float* __restrict__ bk,
    const float* __restrict__ bv,
    f16* __restrict__ Qh, f16* __restrict__ Kh, f16* __restrict__ Vt)
{
    __shared__ __align__(16) char AsB[65536];   // [2 par][2 kh][256 rows][64 B]
    __shared__ __align__(16) char BsB[49152];   // [2 par][2 kh][192 rows][64 B]

    const int tid  = threadIdx.x;
    const int lane = tid & 63;
    const int w    = tid >> 6;          // 0..7
    const int wm   = w >> 2;            // 0..1 (M half, 128 rows)
    const int wn   = w & 3;             // 0..3 (N quarter, 48 cols)
    const int quad = lane >> 4;
    const int ln   = lane & 15;

    // XCD swizzle: 256 blocks -> 8 XCDs x 32 contiguous tiles
    const int bid = blockIdx.x;
    const int swz = (bid & 7) * 32 + (bid >> 3);
    const int m0  = (swz >> 4) * 256;
    const int c0  = (swz & 15) * 192;

    // staging source: linear LDS granule g holds logical element f(16g)
    const int Lr0 = tid * 16;
    const int P0s = Lr0 ^ (((Lr0 >> 7) & 3) << 4);
    const int rA0 = P0s >> 6;           // 0..127
    const int ko0 = (P0s & 63) >> 1;    // f16 index within 32-k half

    const u16* xa0h = Xhi + (size_t)(m0 + rA0)       * D_ + ko0;
    const u16* xa1h = Xhi + (size_t)(m0 + 128 + rA0) * D_ + ko0;
    const u16* xa0l = Xlo + (size_t)(m0 + rA0)       * D_ + ko0;
    const u16* xa1l = Xlo + (size_t)(m0 + 128 + rA0) * D_ + ko0;
    const u16* wb0  = Wt  + (size_t)(c0 + rA0)       * D_ + ko0;
    const u16* wb1  = Wt  + (size_t)(c0 + 128 + rA0) * D_ + ko0;  // tid<256 only

    const int ldw0 = w * 1024;          // wave-uniform LDS sub-bases
    const int ldw1 = 8192 + w * 1024;

    f32x4 acc[8][3];
    #pragma unroll
    for (int i = 0; i < 8; ++i)
        #pragma unroll
        for (int j = 0; j < 3; ++j)
            acc[i][j] = (f32x4){0.f, 0.f, 0.f, 0.f};

    // prologue: tile0 complete + tile1.k0; wait leaves only tile1.k0 in flight
    STAGE_A(0, 0); STAGE_B(0, 0); STAGE_A(0, 1); STAGE_B(0, 1);
    STAGE_A(1, 0); STAGE_B(1, 0);
    asm volatile("s_waitcnt vmcnt(3)" ::: "memory");
    BAR();

    half8 b0[3], b1[3], a0[4], a1[4], a2[4], a3[4];
    RD_B(b0, BsB); RD_A(a0, AsB, 0);     // tile0 kh0 frags (only exposed reads)

    for (int t = 0; t < 32; ++t){
        const char* Ab = AsB + ((t & 1) ? 32768 : 0);
        const char* Bb = BsB + ((t & 1) ? 24576 : 0);
        const char* An = AsB + ((t & 1) ? 0 : 32768);   // next tile's buffers
        const char* Bn = BsB + ((t & 1) ? 0 : 24576);

        // ---- P0: MFMA(kh0, m0-3) ; preload a1 ; stage (t+1).A.k1 ----
        if (t < 31) STAGE_A(t + 1, 1);
        BAR();
        __builtin_amdgcn_s_setprio(1);
        RD_A(a1, Ab, 64);
        MFMA12(a0, b0, 0);
        __builtin_amdgcn_s_setprio(0);
        BAR();

        // ---- P1: MFMA(kh0, m4-7) ; preload b1,a2 ; stage (t+1).B.k1 ----
        if (t < 31) STAGE_B(t + 1, 1);
        BAR();
        __builtin_amdgcn_s_setprio(1);
        RD_B(b1, Bb + 12288);
        RD_A(a2, Ab + 16384, 0);
        MFMA12(a1, b0, 4);
        __builtin_amdgcn_s_setprio(0);
        BAR();

        // ---- P2: MFMA(kh1, m0-3) ; preload a3 ; stage (t+2).A.k0 ----
        if (t < 30) STAGE_A(t + 2, 0);
        BAR();
        __builtin_amdgcn_s_setprio(1);
        RD_A(a3, Ab + 16384, 64);
        MFMA12(a2, b1, 0);
        __builtin_amdgcn_s_setprio(0);
        BAR();

        // ---- P3: MFMA(kh1, m4-7) ; boundary wait ; preload next-tile kh0 ----
        if (t < 30) STAGE_B(t + 2, 0);
        if (t < 30) { asm volatile("s_waitcnt vmcnt(3)" ::: "memory"); }
        else        { asm volatile("s_waitcnt vmcnt(0)" ::: "memory"); }
        BAR();
        __builtin_amdgcn_s_setprio(1);
        RD_B(b0, Bn);                    // next tile kh0 (landed per vmcnt+bar)
        RD_A(a0, An, 0);
        MFMA12(a3, b1, 4);
        __builtin_amdgcn_s_setprio(0);
        BAR();
    }

    // epilogue: 8 m-frags x 3 n-frags (math identical to R0/R1)
    const float QSCALE = 0.125f * 1.44269504088896340736f;
    const float INV64  = 0.015625f;
    #pragma unroll
    for (int nf = 0; nf < 3; ++nf){
        int colg  = c0 + wn * 48 + nf * 16 + ln;
        int which = colg >> 10;          // uniform within the 16-col group
        int h     = (colg >> 6) & 15;
        int e     = colg & 63;
        const float* bp = (which == 0) ? bq : (which == 1) ? bk : bv;
        float bias = bp[h * DH_ + e];
        if (which < 2){
            f16* op = (which == 0) ? Qh : Kh;
            float scale = (which == 0) ? QSCALE : 1.0f;
            #pragma unroll
            for (int mf = 0; mf < 8; ++mf)
                #pragma unroll
                for (int r = 0; r < 4; ++r){
                    int sg = m0 + wm * 128 + mf * 16 + 4 * quad + r;
                    int b  = sg >> 11;
                    int s  = sg & (S_ - 1);
                    float val = (acc[mf][nf][r] * INV64 + bias) * scale;
                    op[((size_t)(b * H_ + h) * S_ + s) * DH_ + e] = (f16)val;
                }
        } else {
            // V: write transposed Vt[bh][e][t]; 4 consecutive s -> 8B store
            #pragma unroll
            for (int mf = 0; mf < 8; ++mf){
                int sg0 = m0 + wm * 128 + mf * 16 + 4 * quad;
                int b   = sg0 >> 11;
                int s0  = sg0 & (S_ - 1);
                u16 p[4];
                #pragma unroll
                for (int r = 0; r < 4; ++r)
                    p[r] = h_bits((f16)(acc[mf][nf][r] * INV64 + bias));
                uint2 pk;
                pk.x = p[0] | ((u32)p[1] << 16);
                pk.y = p[2] | ((u32)p[3] << 16);
                *(uint2*)((u16*)Vt + ((size_t)((b * H_ + h) * DH_ + e)) * S_ + s0) = pk;
            }
        }
    }
}

// ---------------------------------------------------------------------------
// Kernel 3: attention (UNCHANGED).
// ---------------------------------------------------------------------------
#define AKS 72

__global__ __launch_bounds__(256, 4) void attn_kernel(
    const f16* __restrict__ Qh, const f16* __restrict__ Kh,
    const f16* __restrict__ Vt, float* __restrict__ Out)
{
    __shared__ u16 Ks[64 * AKS];   // K tile [t][e]
    __shared__ u16 Vs[64 * AKS];   // V tile [e][t]

    const int tid  = threadIdx.x;
    const int lane = tid & 63;
    const int w    = tid >> 6;
    const int quad = lane >> 4;
    const int ln   = lane & 15;
    const int hb   = blockIdx.x;            // b*H + h  (XCD = hb % 8)
    const int i    = blockIdx.y;            // pair index
    const int h    = hb & 15;
    const int b    = hb >> 4;
    const int bh   = hb;
    const int sub  = w & 1;
    const int qbase = (w >> 1) ? (S_ - 32 * (i + 1) + 16 * sub)
                               : (32 * i + 16 * sub);
    const int vmax  = S_ - 32 * i - 1;      // highest t any wave's PV needs

    const u16* Qg = (const u16*)Qh + (size_t)bh * S_ * DH_;
    const u16* Kg = (const u16*)Kh + (size_t)bh * S_ * DH_;
    const u16* Vg = (const u16*)Vt + (size_t)bh * DH_ * S_;

    // Q fragments straight from global (B-operand: n=q=ln, k=d=32ks+8quad+j)
    half8 qf[2];
    #pragma unroll
    for (int ks = 0; ks < 2; ++ks)
        qf[ks] = __builtin_bit_cast(half8,
            *(const uint4*)(Qg + (size_t)(qbase + ln) * DH_ + 32 * ks + 8 * quad));

    // staging coords: thread covers K rows kr,kr+32 / V rows (e) kr,kr+32
    const int kr = tid >> 3;
    const int kc = (tid & 7) * 8;

    // prefetch tile 0 into registers
    uint4 kA = *(const uint4*)(Kg + (size_t)kr * DH_ + kc);
    uint4 kB = *(const uint4*)(Kg + (size_t)(kr + 32) * DH_ + kc);
    uint4 vA = *(const uint4*)(Vg + (size_t)kr * S_ + kc);
    uint4 vB = *(const uint4*)(Vg + (size_t)(kr + 32) * S_ + kc);

    float l_r = 0.f;
    f32x4 o_acc[4];
    #pragma unroll
    for (int nt = 0; nt < 4; ++nt) o_acc[nt] = (f32x4){0.f, 0.f, 0.f, 0.f};

    const int qrow   = qbase + ln;     // this lane's q (n-dim)
    const int pv_lim = qbase + 15;     // wave-uniform PV bound

    for (int t0 = 0; t0 < S_; t0 += 64){
        __syncthreads();               // all waves done reading prev tile
        *(uint4*)&Ks[kr * AKS + kc]        = kA;
        *(uint4*)&Ks[(kr + 32) * AKS + kc] = kB;
        if (t0 <= vmax){
            *(uint4*)&Vs[kr * AKS + kc]        = vA;
            *(uint4*)&Vs[(kr + 32) * AKS + kc] = vB;
        }
        // prefetch tile t0+64 (hidden behind this tile's compute)
        const int tn = t0 + 64;
        if (tn < S_){
            kA = *(const uint4*)(Kg + (size_t)(tn + kr) * DH_ + kc);
            kB = *(const uint4*)(Kg + (size_t)(tn + kr + 32) * DH_ + kc);
            if (tn <= vmax){
                vA = *(const uint4*)(Vg + (size_t)kr * S_ + tn + kc);
                vB = *(const uint4*)(Vg + (size_t)(kr + 32) * S_ + tn + kc);
            }
        }
        __syncthreads();               // LDS tile ready

        // S^T tile: A = K frags (m=t), B = Q frags (n=q), K=32 over d
        f32x4 sc[4];
        #pragma unroll
        for (int mt = 0; mt < 4; ++mt) sc[mt] = (f32x4){0.f, 0.f, 0.f, 0.f};
        #pragma unroll
        for (int ks = 0; ks < 2; ++ks)
            #pragma unroll
            for (int mt = 0; mt < 4; ++mt){
                half8 kf = __builtin_bit_cast(half8,
                    *(const uint4*)&Ks[(16 * mt + ln) * AKS + 32 * ks + 8 * quad]);
                sc[mt] = __builtin_amdgcn_mfma_f32_16x16x32_f16(kf, qf[ks], sc[mt], 0, 0, 0);
            }

        // p = exp2(s); denominator = plain running row-sum over ALL t
        #pragma unroll
        for (int mt = 0; mt < 4; ++mt)
            #pragma unroll
            for (int r = 0; r < 4; ++r)
                sc[mt][r] = EXP2(sc[mt][r]);
        float s = ((sc[0][0] + sc[0][1] + sc[0][2] + sc[0][3]) +
                   (sc[1][0] + sc[1][1] + sc[1][2] + sc[1][3])) +
                  ((sc[2][0] + sc[2][1] + sc[2][2] + sc[2][3]) +
                   (sc[3][0] + sc[3][1] + sc[3][2] + sc[3][3]));
        s += __shfl_xor(s, 16);
        s += __shfl_xor(s, 32);
        l_r += s;

        // PV per 16-t subtile; only the subtile starting AT qbase is partial
        #pragma unroll
        for (int mt = 0; mt < 4; ++mt){
            const int ts = t0 + 16 * mt;
            if (ts <= pv_lim){         // wave-uniform
                half4 pf;
                if (ts == qbase){      // wave-uniform: the one partial subtile
                    int tb = ts + 4 * quad;
                    #pragma unroll
                    for (int r = 0; r < 4; ++r)
                        pf[r] = (tb + r > qrow) ? (f16)0.f : (f16)sc[mt][r];
                } else {               // fully below diagonal: plain convert
                    #pragma unroll
                    for (int r = 0; r < 4; ++r)
                        pf[r] = (f16)sc[mt][r];
                }
                #pragma unroll
                for (int nt = 0; nt < 4; ++nt){
                    half4 vf = __builtin_bit_cast(half4,
                        *(const uint2*)&Vs[(16 * nt + ln) * AKS + 16 * mt + 4 * quad]);
                    o_acc[nt] = __builtin_amdgcn_mfma_f32_16x16x16f16(pf, vf, o_acc[nt], 0, 0, 0);
                }
            }
        }
    }

    // epilogue: o rows at q = qbase+4quad+r; l lives at lane ln=row
    #pragma unroll
    for (int r = 0; r < 4; ++r){
        float lv  = __shfl(l_r, (lane & 48) | (4 * quad + r));
        float inv = 1.0f / lv;
        int sg = qbase + 4 * quad + r;
        float* op = Out + ((size_t)b * S_ + sg) * D_ + h * DH_;
        #pragma unroll
        for (int nt = 0; nt < 4; ++nt)
            op[16 * nt + ln] = o_acc[nt][r] * inv;
    }
}

// ---------------------------------------------------------------------------
extern "C" void kernel_launch(void* const* d_in, const int* in_sizes, int n_in,
                              void* d_out, int out_size, void* d_ws, size_t ws_size,
                              hipStream_t stream)
{
    const float* X  = (const float*)d_in[0];
    const float* Wq = (const float*)d_in[1];
    const float* bq = (const float*)d_in[2];
    const float* Wk = (const float*)d_in[3];
    const float* bk = (const float*)d_in[4];
    const float* Wv = (const float*)d_in[5];
    const float* bv = (const float*)d_in[6];
    float* out = (float*)d_out;

    // workspace (46 MiB): Wt | Qh | Kh | Vt | Xhi | Xlo  (unchanged layout)
    u16* Wt  = (u16*)d_ws;                    // 3,145,728 u16
    f16* Qh  = (f16*)(Wt + 3145728);
    f16* Kh  = Qh + 4194304;
    f16* Vt  = Kh + 4194304;
    u16* Xhi = (u16*)(Vt + 4194304);
    u16* Xlo = Xhi + 4194304;

    prep_kernel<<<dim3(4096 + 768), 256, 0, stream>>>(X, Wq, Wk, Wv, Xhi, Xlo, Wt);
    proj_kernel<<<dim3(256), dim3(512), 0, stream>>>(Xhi, Xlo, Wt, bq, bk, bv, Qh, Kh, Vt);
    attn_kernel<<<dim3(32, 32), 256, 0, stream>>>(Qh, Kh, Vt, out);
}